// Round 8
// baseline (154.526 us; speedup 1.0000x reference)
//
#include <hip/hip_runtime.h>

typedef unsigned short u16;
typedef float  f32x4  __attribute__((ext_vector_type(4)));
typedef float  f32x16 __attribute__((ext_vector_type(16)));
typedef short  s16x8  __attribute__((ext_vector_type(8)));
typedef unsigned int u32x2 __attribute__((ext_vector_type(2)));
typedef unsigned int u32x4 __attribute__((ext_vector_type(4)));

union U8 { u32x4 u; u32x2 u2[2]; s16x8 s; unsigned int uw[4]; };

// f32 -> bf16 bits, RTNE (inputs have no NaN/Inf)
__device__ __forceinline__ u16 f2bs(float f) {
    union { float f; unsigned int u; } x; x.f = f;
    return (u16)((x.u + 0x7FFFu + ((x.u >> 16) & 1u)) >> 16);
}

// packed RTNE f32x2 -> bf16x2
__device__ __forceinline__ unsigned int cvtpk(float a, float b) {
    unsigned int r;
    asm("v_cvt_pk_bf16_f32 %0, %1, %2" : "=v"(r) : "v"(a), "v"(b));
    return r;
}

#if __has_builtin(__builtin_amdgcn_exp2f)
#define EXP2(v) __builtin_amdgcn_exp2f(v)
#else
#define EXP2(v) exp2f(v)
#endif

__device__ __forceinline__ f32x4 mfma16(s16x8 a, s16x8 b, f32x4 c) {
    return __builtin_amdgcn_mfma_f32_16x16x32_bf16(a, b, c, 0, 0, 0);
}
__device__ __forceinline__ f32x16 mfma32(s16x8 a, s16x8 b, f32x16 c) {
    return __builtin_amdgcn_mfma_f32_32x32x16_bf16(a, b, c, 0, 0, 0);
}

// async global -> LDS, 16B per lane; lds base must be wave-uniform (HW adds lane*16)
typedef __attribute__((address_space(3))) unsigned int lds_u32;
typedef const __attribute__((address_space(1))) unsigned int glb_u32;
__device__ __forceinline__ void gl16(const u16* g, u16* l) {
    __builtin_amdgcn_global_load_lds((glb_u32*)g, (lds_u32*)l, 16, 0, 0);
}

// ---------------- pack weights via LDS transpose
__global__ __launch_bounds__(256) void pack_w2(const float* __restrict__ Wq,
                                               const float* __restrict__ Wk,
                                               const float* __restrict__ Wv,
                                               const float* __restrict__ Wo,
                                               u16* __restrict__ Wt) {
    __shared__ float tile[64][65];
    const int bid = blockIdx.x, tid = threadIdx.x;
    const float* src; u16* dst; int src_ld, sr0, sc0;
    if (bid < 108) {
        int tensor = bid / 36, rem = bid % 36, h = rem / 6, ct = rem % 6;
        const float* W = (tensor == 0) ? Wq : (tensor == 1) ? Wk : Wv;
        src = W + h * 24576; src_ld = 64; sr0 = ct * 64; sc0 = 0;
        dst = Wt + tensor * 147456 + h * 24576;
    } else {
        int rem = bid - 108, et = rem / 6, ft = rem % 6;
        src = Wo; src_ld = 384; sr0 = ft * 64; sc0 = et * 64;
        dst = Wt + 3 * 147456;
    }
    const int r = tid >> 2, cb = (tid & 3) * 16;
    const float* sp = src + (size_t)(sr0 + r) * src_ld + sc0 + cb;
    #pragma unroll
    for (int j = 0; j < 4; ++j)
        *(f32x4*)&tile[r][cb + j * 4] = *(const f32x4*)(sp + j * 4);
    __syncthreads();
    struct alignas(16) OV { u16 v[16]; } ov;
    #pragma unroll
    for (int j = 0; j < 16; ++j) ov.v[j] = f2bs(tile[cb + j][r]);
    u16* dp = dst + (size_t)(sc0 + r) * 384 + sr0 + cb;
    *(u32x4*)dp       = *(u32x4*)&ov.v[0];
    *(u32x4*)(dp + 8) = *(u32x4*)&ov.v[8];
}

// ---------------- x fp32 -> bf16
__global__ __launch_bounds__(256) void convert_x(const float* __restrict__ x, u16* __restrict__ xb) {
    const int i = (blockIdx.x * 256 + threadIdx.x) * 8;
    f32x4 a = *(const f32x4*)(x + i);
    f32x4 b = *(const f32x4*)(x + i + 4);
    U8 o;
    #pragma unroll
    for (int j = 0; j < 4; ++j) { o.s[j] = (short)f2bs(a[j]); o.s[4 + j] = (short)f2bs(b[j]); }
    *(u32x4*)(xb + i) = o.u;
}

// ---------------- QKV projection: xb[8192,384] @ Wt^T -> Qb/Kb/Vb [bh][t][64] bf16
__global__ __launch_bounds__(256) void proj2(const u16* __restrict__ xb,
                                             const u16* __restrict__ Wt,
                                             u16* __restrict__ Qb,
                                             u16* __restrict__ Kb,
                                             u16* __restrict__ Vb) {
    __shared__ u16 As[2][128 * 32];
    __shared__ u16 Bs[2][128 * 32];
    const int tid = threadIdx.x, w = tid >> 6, lane = tid & 63;
    const int lr = lane & 15, lg = lane >> 4;
    const int wr = w >> 1, wc = w & 1;
    const int mt = blockIdx.x, nt = blockIdx.y;          // grid (64, 9)
    const int m0 = mt * 128, n0 = nt * 128;

    const int c0 = w * 2 * 64 + lane;
    const int ar0 = c0 >> 2, acc0 = c0 & 3;
    const int c1 = c0 + 64;
    const int ar1 = c1 >> 2, acc1 = c1 & 3;
    const u16* gA0 = xb + (size_t)(m0 + ar0) * 384 + acc0 * 8;
    const u16* gA1 = xb + (size_t)(m0 + ar1) * 384 + acc1 * 8;
    const u16* gB0 = Wt + (size_t)(n0 + ar0) * 384 + acc0 * 8;
    const u16* gB1 = Wt + (size_t)(n0 + ar1) * 384 + acc1 * 8;

    f32x4 acc[4][4];
    #pragma unroll
    for (int i = 0; i < 4; ++i)
        #pragma unroll
        for (int j = 0; j < 4; ++j) acc[i][j] = f32x4{0.f, 0.f, 0.f, 0.f};

    gl16(gA0, &As[0][(w * 2 + 0) * 512]);
    gl16(gA1, &As[0][(w * 2 + 1) * 512]);
    gl16(gB0, &Bs[0][(w * 2 + 0) * 512]);
    gl16(gB1, &Bs[0][(w * 2 + 1) * 512]);
    __syncthreads();

    for (int kt = 0; kt < 12; ++kt) {
        const int buf = kt & 1;
        if (kt < 11) {
            const int ko = (kt + 1) * 32;
            gl16(gA0 + ko, &As[buf ^ 1][(w * 2 + 0) * 512]);
            gl16(gA1 + ko, &As[buf ^ 1][(w * 2 + 1) * 512]);
            gl16(gB0 + ko, &Bs[buf ^ 1][(w * 2 + 0) * 512]);
            gl16(gB1 + ko, &Bs[buf ^ 1][(w * 2 + 1) * 512]);
        }
        U8 af[4], bf[4];
        #pragma unroll
        for (int f = 0; f < 4; ++f) {
            af[f].u = *(const u32x4*)&As[buf][(wr * 64 + f * 16 + lr) * 32 + lg * 8];
            bf[f].u = *(const u32x4*)&Bs[buf][(wc * 64 + f * 16 + lr) * 32 + lg * 8];
        }
        #pragma unroll
        for (int mf = 0; mf < 4; ++mf)
            #pragma unroll
            for (int nf = 0; nf < 4; ++nf)
                acc[mf][nf] = mfma16(af[mf].s, bf[nf].s, acc[mf][nf]);
        __syncthreads();
    }

    const int tensor = nt / 3;
    u16* dst = (tensor == 0) ? Qb : (tensor == 1) ? Kb : Vb;
    const float scl = (tensor == 0) ? 0.18033688011112042f : 1.0f;   // (1/8)*log2(e) for Q
    const int head_base = (nt % 3) * 2 + wc;
    #pragma unroll
    for (int mf = 0; mf < 4; ++mf)
        #pragma unroll
        for (int nf = 0; nf < 4; ++nf)
            #pragma unroll
            for (int r = 0; r < 4; ++r) {
                int m = m0 + wr * 64 + mf * 16 + lg * 4 + r;
                int b = m >> 11, t = m & 2047;
                int d = nf * 16 + lr;
                dst[((size_t)(b * 6 + head_base) * 2048 + t) * 64 + d] = f2bs(acc[mf][nf][r] * scl);
            }
}

// ---------------- V[bh][t][64] -> Vt[bh][64][pos], key position = per-16 window blocks [0,2,1,3]
__global__ __launch_bounds__(256) void transpose_v(const u16* __restrict__ Vb,
                                                   u16* __restrict__ Vt) {
    __shared__ u16 tile[64][72];
    const int bh = blockIdx.y, t0 = blockIdx.x * 64;
    const int tid = threadIdx.x;
    const int r = tid >> 2, c0 = (tid & 3) * 16;
    const u16* src = Vb + ((size_t)bh * 2048 + t0 + r) * 64 + c0;
    u32x4 a  = *(const u32x4*)(src);
    u32x4 b2 = *(const u32x4*)(src + 8);
    *(u32x4*)&tile[r][c0]     = a;
    *(u32x4*)&tile[r][c0 + 8] = b2;
    __syncthreads();
    struct alignas(16) OutV { u16 v[16]; } ov;
    #pragma unroll
    for (int j = 0; j < 4; ++j) {
        ov.v[j]      = tile[c0 + j][r];
        ov.v[4 + j]  = tile[c0 + 8 + j][r];
        ov.v[8 + j]  = tile[c0 + 4 + j][r];
        ov.v[12 + j] = tile[c0 + 12 + j][r];
    }
    u16* dst = Vt + ((size_t)bh * 64 + r) * 2048 + t0 + c0;
    *(u32x4*)dst       = *(u32x4*)&ov.v[0];
    *(u32x4*)(dst + 8) = *(u32x4*)&ov.v[8];
}

// ---------------- fused attention v6: LDS-free main loop.
// Block = 64 q-rows x 2048 keys, 4 waves; wave = 64q (2 q-subs, K-frag reuse)
// x 512 keys (private quarter). K/V loaded global->reg (L2-resident, XCD-pinned
// grid: blockIdx linear id % 8 == bh % 8). No barriers in the loop; LDS merge at end.
__global__ __launch_bounds__(256, 3) void attn6(const u16* __restrict__ Qb,
                                                const u16* __restrict__ Kb,
                                                const u16* __restrict__ Vt,
                                                u16* __restrict__ AO) {
    __shared__ float ms[8448];        // 2 regions x 4224 (4096 acc + 128 rsum)
    const int tid = threadIdx.x, wv = tid >> 6, lane = tid & 63;
    const int q = lane & 31, hi = lane >> 5;
    const int bh = blockIdx.x, qt = blockIdx.y;   // grid (24, 32)
    const int b = bh / 6, h = bh - b * 6;
    const int qbase = qt * 64;

    // Q B-frags for both q-subs (pre-scaled by (1/8)*log2(e))
    const u16* qp = Qb + ((size_t)bh * 2048 + qbase + q) * 64 + hi * 8;
    U8 bq[2][4];
    #pragma unroll
    for (int qs = 0; qs < 2; ++qs)
        #pragma unroll
        for (int m = 0; m < 4; ++m)
            bq[qs][m].u = *(const u32x4*)(qp + qs * 2048 + m * 16);

    // per-lane global bases for this wave's key quarter
    const u16* kb_l = Kb + (size_t)bh * 131072 + (size_t)wv * 32768 + q * 64 + hi * 8;
    const u16* vb_l = Vt + (size_t)bh * 131072 + (size_t)q * 2048 + wv * 512 + hi * 8;

    f32x16 acc[2][2];                 // [qs][dt2]
    #pragma unroll
    for (int i = 0; i < 2; ++i)
        #pragma unroll
        for (int j = 0; j < 2; ++j)
            #pragma unroll
            for (int r = 0; r < 16; ++r) acc[i][j][r] = 0.f;
    float rs0 = 0.f, rs1 = 0.f;

    #pragma unroll 2
    for (int it = 0; it < 16; ++it) {
        const u16* kp = kb_l + it * 2048;
        U8 kf[4];
        #pragma unroll
        for (int m = 0; m < 4; ++m) kf[m].u = *(const u32x4*)(kp + m * 16);

        f32x16 S0, S1;
        #pragma unroll
        for (int r = 0; r < 16; ++r) { S0[r] = 0.f; S1[r] = 0.f; }
        #pragma unroll
        for (int m = 0; m < 4; ++m) S0 = mfma32(kf[m].s, bq[0][m].s, S0);
        #pragma unroll
        for (int m = 0; m < 4; ++m) S1 = mfma32(kf[m].s, bq[1][m].s, S1);

        float p0[16], p1[16];
        #pragma unroll
        for (int r = 0; r < 16; ++r) { p0[r] = EXP2(S0[r]); p1[r] = EXP2(S1[r]); }
        #pragma unroll
        for (int r = 0; r < 16; ++r) { rs0 += p0[r]; rs1 += p1[r]; }

        U8 pa[2][2];                  // [qs][kg]
        #pragma unroll
        for (int i = 0; i < 4; ++i) {
            pa[0][0].uw[i] = cvtpk(p0[2 * i],     p0[2 * i + 1]);
            pa[0][1].uw[i] = cvtpk(p0[8 + 2 * i], p0[9 + 2 * i]);
            pa[1][0].uw[i] = cvtpk(p1[2 * i],     p1[2 * i + 1]);
            pa[1][1].uw[i] = cvtpk(p1[8 + 2 * i], p1[9 + 2 * i]);
        }

        const int ko = it * 32;
        #pragma unroll
        for (int dt2 = 0; dt2 < 2; ++dt2) {
            U8 bv0, bv1;
            bv0.u = *(const u32x4*)(vb_l + dt2 * 65536 + ko);
            bv1.u = *(const u32x4*)(vb_l + dt2 * 65536 + ko + 16);
            acc[0][dt2] = mfma32(pa[0][0].s, bv0.s, acc[0][dt2]);
            acc[0][dt2] = mfma32(pa[0][1].s, bv1.s, acc[0][dt2]);
            acc[1][dt2] = mfma32(pa[1][0].s, bv0.s, acc[1][dt2]);
            acc[1][dt2] = mfma32(pa[1][1].s, bv1.s, acc[1][dt2]);
        }
    }

    // rowsum across hi halves (both halves then hold rowsum(q) per q-sub)
    rs0 += __shfl_xor(rs0, 32, 64);
    rs1 += __shfl_xor(rs1, 32, 64);

    // ---- 4-way merge tree: wave pairs (1->0, 3->2) then (2->0)
    float* r0 = ms;
    float* r1 = ms + 4224;

    if (wv == 1) {
        #pragma unroll
        for (int qs = 0; qs < 2; ++qs)
            #pragma unroll
            for (int dt2 = 0; dt2 < 2; ++dt2)
                #pragma unroll
                for (int r = 0; r < 16; ++r) {
                    int row = qs * 32 + (r & 3) + 8 * (r >> 2) + 4 * hi;
                    r0[row * 64 + dt2 * 32 + q] = acc[qs][dt2][r];
                }
        r0[4096 + lane] = rs0; r0[4160 + lane] = rs1;
    } else if (wv == 3) {
        #pragma unroll
        for (int qs = 0; qs < 2; ++qs)
            #pragma unroll
            for (int dt2 = 0; dt2 < 2; ++dt2)
                #pragma unroll
                for (int r = 0; r < 16; ++r) {
                    int row = qs * 32 + (r & 3) + 8 * (r >> 2) + 4 * hi;
                    r1[row * 64 + dt2 * 32 + q] = acc[qs][dt2][r];
                }
        r1[4096 + lane] = rs0; r1[4160 + lane] = rs1;
    }
    __syncthreads();
    if (wv == 0) {
        #pragma unroll
        for (int qs = 0; qs < 2; ++qs)
            #pragma unroll
            for (int dt2 = 0; dt2 < 2; ++dt2)
                #pragma unroll
                for (int r = 0; r < 16; ++r) {
                    int row = qs * 32 + (r & 3) + 8 * (r >> 2) + 4 * hi;
                    acc[qs][dt2][r] += r0[row * 64 + dt2 * 32 + q];
                }
        rs0 += r0[4096 + lane]; rs1 += r0[4160 + lane];
    } else if (wv == 2) {
        #pragma unroll
        for (int qs = 0; qs < 2; ++qs)
            #pragma unroll
            for (int dt2 = 0; dt2 < 2; ++dt2)
                #pragma unroll
                for (int r = 0; r < 16; ++r) {
                    int row = qs * 32 + (r & 3) + 8 * (r >> 2) + 4 * hi;
                    acc[qs][dt2][r] += r1[row * 64 + dt2 * 32 + q];
                }
        rs0 += r1[4096 + lane]; rs1 += r1[4160 + lane];
    }
    __syncthreads();
    if (wv == 2) {
        #pragma unroll
        for (int qs = 0; qs < 2; ++qs)
            #pragma unroll
            for (int dt2 = 0; dt2 < 2; ++dt2)
                #pragma unroll
                for (int r = 0; r < 16; ++r) {
                    int row = qs * 32 + (r & 3) + 8 * (r >> 2) + 4 * hi;
                    r0[row * 64 + dt2 * 32 + q] = acc[qs][dt2][r];
                }
        r0[4096 + lane] = rs0; r0[4160 + lane] = rs1;
    }
    __syncthreads();
    if (wv == 0) {
        #pragma unroll
        for (int qs = 0; qs < 2; ++qs)
            #pragma unroll
            for (int dt2 = 0; dt2 < 2; ++dt2)
                #pragma unroll
                for (int r = 0; r < 16; ++r) {
                    int row = qs * 32 + (r & 3) + 8 * (r >> 2) + 4 * hi;
                    acc[qs][dt2][r] += r0[row * 64 + dt2 * 32 + q];
                }
        rs0 += r0[4096 + lane]; rs1 += r0[4160 + lane];

        const float inv0 = 1.0f / rs0;
        const float inv1 = 1.0f / rs1;
        const size_t aobase = ((size_t)b * 2048 + qbase) * 384 + h * 64;
        #pragma unroll
        for (int qs = 0; qs < 2; ++qs)
            #pragma unroll
            for (int r = 0; r < 16; ++r) {
                const int crow = (r & 3) + 8 * (r >> 2) + 4 * hi;
                const int qrow = qs * 32 + crow;
                float vinv = __shfl(qs == 0 ? inv0 : inv1, crow, 64);
                #pragma unroll
                for (int dt2 = 0; dt2 < 2; ++dt2)
                    AO[aobase + (size_t)qrow * 384 + dt2 * 32 + q] = f2bs(acc[qs][dt2][r] * vinv);
            }
    }
}

// ---------------- output projection: AO[8192,384] @ Wot^T + bo -> out fp32
__global__ __launch_bounds__(256) void outproj2(const u16* __restrict__ AO,
                                                const u16* __restrict__ Wot,
                                                const float* __restrict__ bo,
                                                float* __restrict__ out) {
    __shared__ u16 As[2][64 * 32];
    __shared__ u16 Bs[2][64 * 32];
    const int tid = threadIdx.x, w = tid >> 6, lane = tid & 63;
    const int lr = lane & 15, lg = lane >> 4;
    const int wr = w >> 1, wc = w & 1;
    const int mt = blockIdx.x, nt = blockIdx.y;          // grid (128, 6)
    const int m0 = mt * 64, n0 = nt * 64;

    const int c0 = w * 64 + lane;
    const int ar0 = c0 >> 2, cc0 = c0 & 3;
    const u16* gA = AO  + (size_t)(m0 + ar0) * 384 + cc0 * 8;
    const u16* gB = Wot + (size_t)(n0 + ar0) * 384 + cc0 * 8;

    f32x4 acc[2][2];
    #pragma unroll
    for (int i = 0; i < 2; ++i)
        #pragma unroll
        for (int j = 0; j < 2; ++j) acc[i][j] = f32x4{0.f, 0.f, 0.f, 0.f};

    gl16(gA, &As[0][w * 512]);
    gl16(gB, &Bs[0][w * 512]);
    __syncthreads();

    for (int kt = 0; kt < 12; ++kt) {
        const int buf = kt & 1;
        if (kt < 11) {
            const int ko = (kt + 1) * 32;
            gl16(gA + ko, &As[buf ^ 1][w * 512]);
            gl16(gB + ko, &Bs[buf ^ 1][w * 512]);
        }
        U8 af[2], bf[2];
        #pragma unroll
        for (int f = 0; f < 2; ++f) {
            af[f].u = *(const u32x4*)&As[buf][(wr * 32 + f * 16 + lr) * 32 + lg * 8];
            bf[f].u = *(const u32x4*)&Bs[buf][(wc * 32 + f * 16 + lr) * 32 + lg * 8];
        }
        #pragma unroll
        for (int mf = 0; mf < 2; ++mf)
            #pragma unroll
            for (int nf = 0; nf < 2; ++nf)
                acc[mf][nf] = mfma16(af[mf].s, bf[nf].s, acc[mf][nf]);
        __syncthreads();
    }

    #pragma unroll
    for (int mf = 0; mf < 2; ++mf)
        #pragma unroll
        for (int nf = 0; nf < 2; ++nf) {
            int col = n0 + wc * 32 + nf * 16 + lr;
            float bias = bo[col];
            #pragma unroll
            for (int r = 0; r < 4; ++r) {
                int m = m0 + wr * 32 + mf * 16 + lg * 4 + r;
                out[(size_t)m * 384 + col] = acc[mf][nf][r] + bias;
            }
        }
}

extern "C" void kernel_launch(void* const* d_in, const int* in_sizes, int n_in,
                              void* d_out, int out_size, void* d_ws, size_t ws_size,
                              hipStream_t stream) {
    const float* x  = (const float*)d_in[0];
    const float* Wq = (const float*)d_in[1];
    const float* Wk = (const float*)d_in[2];
    const float* Wv = (const float*)d_in[3];
    const float* Wo = (const float*)d_in[4];
    const float* bo = (const float*)d_in[5];
    float* out = (float*)d_out;
    char* ws = (char*)d_ws;

    u16* Wt  = (u16*)(ws);                    // [1152][384] bf16 (Wq|Wk|Wv heads-major, then Wo^T)
    u16* Wot = (u16*)(ws + 884736);
    u16* xb  = (u16*)(ws + 1179648);          // [8192][384] bf16
    u16* Qb  = (u16*)(ws + 7471104);          // [24][2048][64] bf16
    u16* Kb  = (u16*)(ws + 13762560);
    u16* Vb  = (u16*)(ws + 20054016);
    u16* Vt  = (u16*)(ws + 26345472);         // [24][64][2048] bf16 (key positions permuted)
    u16* AO  = (u16*)(ws + 1179648);          // reuses xb slot (xb dead after proj2)

    pack_w2<<<144, 256, 0, stream>>>(Wq, Wk, Wv, Wo, Wt);
    convert_x<<<1536, 256, 0, stream>>>(x, xb);
    proj2<<<dim3(64, 9), 256, 0, stream>>>(xb, Wt, Qb, Kb, Vb);
    transpose_v<<<dim3(32, 24), 256, 0, stream>>>(Vb, Vt);
    attn6<<<dim3(24, 32), 256, 0, stream>>>(Qb, Kb, Vt, AO);
    outproj2<<<dim3(128, 6), 256, 0, stream>>>(AO, Wot, bo, out);
}

// Round 10
// 138.878 us; speedup vs baseline: 1.1127x; 1.1127x over previous
//
#include <hip/hip_runtime.h>

typedef unsigned short u16;
typedef float  f32x4  __attribute__((ext_vector_type(4)));
typedef float  f32x16 __attribute__((ext_vector_type(16)));
typedef short  s16x8  __attribute__((ext_vector_type(8)));
typedef unsigned int u32x2 __attribute__((ext_vector_type(2)));
typedef unsigned int u32x4 __attribute__((ext_vector_type(4)));

union U8 { u32x4 u; u32x2 u2[2]; s16x8 s; unsigned int uw[4]; };

// f32 -> bf16 bits, RTNE (inputs have no NaN/Inf)
__device__ __forceinline__ u16 f2bs(float f) {
    union { float f; unsigned int u; } x; x.f = f;
    return (u16)((x.u + 0x7FFFu + ((x.u >> 16) & 1u)) >> 16);
}

// packed RTNE f32x2 -> bf16x2
__device__ __forceinline__ unsigned int cvtpk(float a, float b) {
    unsigned int r;
    asm("v_cvt_pk_bf16_f32 %0, %1, %2" : "=v"(r) : "v"(a), "v"(b));
    return r;
}

#if __has_builtin(__builtin_amdgcn_exp2f)
#define EXP2(v) __builtin_amdgcn_exp2f(v)
#else
#define EXP2(v) exp2f(v)
#endif

__device__ __forceinline__ f32x4 mfma16(s16x8 a, s16x8 b, f32x4 c) {
    return __builtin_amdgcn_mfma_f32_16x16x32_bf16(a, b, c, 0, 0, 0);
}
__device__ __forceinline__ f32x16 mfma32(s16x8 a, s16x8 b, f32x16 c) {
    return __builtin_amdgcn_mfma_f32_32x32x16_bf16(a, b, c, 0, 0, 0);
}

// async global -> LDS, 16B per lane; lds base must be wave-uniform (HW adds lane*16)
typedef __attribute__((address_space(3))) unsigned int lds_u32;
typedef const __attribute__((address_space(1))) unsigned int glb_u32;
__device__ __forceinline__ void gl16(const u16* g, u16* l) {
    __builtin_amdgcn_global_load_lds((glb_u32*)g, (lds_u32*)l, 16, 0, 0);
}

// ---------------- pack weights via LDS transpose
__global__ __launch_bounds__(256) void pack_w2(const float* __restrict__ Wq,
                                               const float* __restrict__ Wk,
                                               const float* __restrict__ Wv,
                                               const float* __restrict__ Wo,
                                               u16* __restrict__ Wt) {
    __shared__ float tile[64][65];
    const int bid = blockIdx.x, tid = threadIdx.x;
    const float* src; u16* dst; int src_ld, sr0, sc0;
    if (bid < 108) {
        int tensor = bid / 36, rem = bid % 36, h = rem / 6, ct = rem % 6;
        const float* W = (tensor == 0) ? Wq : (tensor == 1) ? Wk : Wv;
        src = W + h * 24576; src_ld = 64; sr0 = ct * 64; sc0 = 0;
        dst = Wt + tensor * 147456 + h * 24576;
    } else {
        int rem = bid - 108, et = rem / 6, ft = rem % 6;
        src = Wo; src_ld = 384; sr0 = ft * 64; sc0 = et * 64;
        dst = Wt + 3 * 147456;
    }
    const int r = tid >> 2, cb = (tid & 3) * 16;
    const float* sp = src + (size_t)(sr0 + r) * src_ld + sc0 + cb;
    #pragma unroll
    for (int j = 0; j < 4; ++j)
        *(f32x4*)&tile[r][cb + j * 4] = *(const f32x4*)(sp + j * 4);
    __syncthreads();
    struct alignas(16) OV { u16 v[16]; } ov;
    #pragma unroll
    for (int j = 0; j < 16; ++j) ov.v[j] = f2bs(tile[cb + j][r]);
    u16* dp = dst + (size_t)(sc0 + r) * 384 + sr0 + cb;
    *(u32x4*)dp       = *(u32x4*)&ov.v[0];
    *(u32x4*)(dp + 8) = *(u32x4*)&ov.v[8];
}

// ---------------- x fp32 -> bf16
__global__ __launch_bounds__(256) void convert_x(const float* __restrict__ x, u16* __restrict__ xb) {
    const int i = (blockIdx.x * 256 + threadIdx.x) * 8;
    f32x4 a = *(const f32x4*)(x + i);
    f32x4 b = *(const f32x4*)(x + i + 4);
    U8 o;
    #pragma unroll
    for (int j = 0; j < 4; ++j) { o.s[j] = (short)f2bs(a[j]); o.s[4 + j] = (short)f2bs(b[j]); }
    *(u32x4*)(xb + i) = o.u;
}

// ---------------- QKV projection: xb[8192,384] @ Wt^T -> Qb/Kb/Vb [bh][t][64] bf16
__global__ __launch_bounds__(256) void proj2(const u16* __restrict__ xb,
                                             const u16* __restrict__ Wt,
                                             u16* __restrict__ Qb,
                                             u16* __restrict__ Kb,
                                             u16* __restrict__ Vb) {
    __shared__ u16 As[2][128 * 32];
    __shared__ u16 Bs[2][128 * 32];
    const int tid = threadIdx.x, w = tid >> 6, lane = tid & 63;
    const int lr = lane & 15, lg = lane >> 4;
    const int wr = w >> 1, wc = w & 1;
    const int mt = blockIdx.x, nt = blockIdx.y;          // grid (64, 9)
    const int m0 = mt * 128, n0 = nt * 128;

    const int c0 = w * 2 * 64 + lane;
    const int ar0 = c0 >> 2, acc0 = c0 & 3;
    const int c1 = c0 + 64;
    const int ar1 = c1 >> 2, acc1 = c1 & 3;
    const u16* gA0 = xb + (size_t)(m0 + ar0) * 384 + acc0 * 8;
    const u16* gA1 = xb + (size_t)(m0 + ar1) * 384 + acc1 * 8;
    const u16* gB0 = Wt + (size_t)(n0 + ar0) * 384 + acc0 * 8;
    const u16* gB1 = Wt + (size_t)(n0 + ar1) * 384 + acc1 * 8;

    f32x4 acc[4][4];
    #pragma unroll
    for (int i = 0; i < 4; ++i)
        #pragma unroll
        for (int j = 0; j < 4; ++j) acc[i][j] = f32x4{0.f, 0.f, 0.f, 0.f};

    gl16(gA0, &As[0][(w * 2 + 0) * 512]);
    gl16(gA1, &As[0][(w * 2 + 1) * 512]);
    gl16(gB0, &Bs[0][(w * 2 + 0) * 512]);
    gl16(gB1, &Bs[0][(w * 2 + 1) * 512]);
    __syncthreads();

    for (int kt = 0; kt < 12; ++kt) {
        const int buf = kt & 1;
        if (kt < 11) {
            const int ko = (kt + 1) * 32;
            gl16(gA0 + ko, &As[buf ^ 1][(w * 2 + 0) * 512]);
            gl16(gA1 + ko, &As[buf ^ 1][(w * 2 + 1) * 512]);
            gl16(gB0 + ko, &Bs[buf ^ 1][(w * 2 + 0) * 512]);
            gl16(gB1 + ko, &Bs[buf ^ 1][(w * 2 + 1) * 512]);
        }
        U8 af[4], bf[4];
        #pragma unroll
        for (int f = 0; f < 4; ++f) {
            af[f].u = *(const u32x4*)&As[buf][(wr * 64 + f * 16 + lr) * 32 + lg * 8];
            bf[f].u = *(const u32x4*)&Bs[buf][(wc * 64 + f * 16 + lr) * 32 + lg * 8];
        }
        #pragma unroll
        for (int mf = 0; mf < 4; ++mf)
            #pragma unroll
            for (int nf = 0; nf < 4; ++nf)
                acc[mf][nf] = mfma16(af[mf].s, bf[nf].s, acc[mf][nf]);
        __syncthreads();
    }

    const int tensor = nt / 3;
    u16* dst = (tensor == 0) ? Qb : (tensor == 1) ? Kb : Vb;
    const float scl = (tensor == 0) ? 0.18033688011112042f : 1.0f;   // (1/8)*log2(e) for Q
    const int head_base = (nt % 3) * 2 + wc;
    #pragma unroll
    for (int mf = 0; mf < 4; ++mf)
        #pragma unroll
        for (int nf = 0; nf < 4; ++nf)
            #pragma unroll
            for (int r = 0; r < 4; ++r) {
                int m = m0 + wr * 64 + mf * 16 + lg * 4 + r;
                int b = m >> 11, t = m & 2047;
                int d = nf * 16 + lr;
                dst[((size_t)(b * 6 + head_base) * 2048 + t) * 64 + d] = f2bs(acc[mf][nf][r] * scl);
            }
}

// ---------------- V[bh][t][64] -> Vt[bh][64][pos], key position = per-16 window blocks [0,2,1,3]
__global__ __launch_bounds__(256) void transpose_v(const u16* __restrict__ Vb,
                                                   u16* __restrict__ Vt) {
    __shared__ u16 tile[64][72];
    const int bh = blockIdx.y, t0 = blockIdx.x * 64;
    const int tid = threadIdx.x;
    const int r = tid >> 2, c0 = (tid & 3) * 16;
    const u16* src = Vb + ((size_t)bh * 2048 + t0 + r) * 64 + c0;
    u32x4 a  = *(const u32x4*)(src);
    u32x4 b2 = *(const u32x4*)(src + 8);
    *(u32x4*)&tile[r][c0]     = a;
    *(u32x4*)&tile[r][c0 + 8] = b2;
    __syncthreads();
    struct alignas(16) OutV { u16 v[16]; } ov;
    #pragma unroll
    for (int j = 0; j < 4; ++j) {
        ov.v[j]      = tile[c0 + j][r];
        ov.v[4 + j]  = tile[c0 + 8 + j][r];
        ov.v[8 + j]  = tile[c0 + 4 + j][r];
        ov.v[12 + j] = tile[c0 + 12 + j][r];
    }
    u16* dst = Vt + ((size_t)bh * 64 + r) * 2048 + t0 + c0;
    *(u32x4*)dst       = *(u32x4*)&ov.v[0];
    *(u32x4*)(dst + 8) = *(u32x4*)&ov.v[8];
}

// ---------------- fused attention v4 + XCD-pinned grid: 32x32x16 MFMA,
// block = 4 waves (2 qsub x 2 khalf), KVBLK=32, dbuf LDS 32KB, key-half merge via LDS.
// grid (24,32) bh-major: all 32 blocks of one bh land on XCD bh%8 -> K/V L2-resident.
__global__ __launch_bounds__(256) void attn4(const u16* __restrict__ Qb,
                                             const u16* __restrict__ Kb,
                                             const u16* __restrict__ Vt,
                                             u16* __restrict__ AO) {
    // [buf 16KB] x2 : K at kh*4096 (32 rows x 128B, chunk^=(row&7)) ; V at 8192+kh*4096 (64 rows x 64B, chunk^=(row&3))
    __shared__ char smem[32768];
    const int tid = threadIdx.x, wv = tid >> 6, lane = tid & 63;
    const int qs = wv >> 1, kh = wv & 1;
    const int q = lane & 31, hi = lane >> 5;
    const int bh = blockIdx.x, qt = blockIdx.y;   // grid (24, 32): linear%8 == bh%8 -> XCD-pinned
    const int b = bh / 6, h = bh - b * 6;
    const int qbase = qt * 64 + qs * 32;

    // Q B-frags: Q[qbase+q][m*16 + hi*8 + j], pre-scaled by (1/8)*log2(e)
    const u16* qp = Qb + ((size_t)bh * 2048 + qbase + q) * 64 + hi * 8;
    U8 bq[4];
    #pragma unroll
    for (int m = 0; m < 4; ++m) bq[m].u = *(const u32x4*)(qp + m * 16);

    // staging: wave (qs,kh) stages its kh region: K rows qs*16..+15, V rows qs*32..+31
    const int l8 = lane >> 3, c8 = lane & 7;        // K: 8 rows x 8 chunks / 1KB
    const int kr = qs * 16 + l8;
    const u16* ksrc = Kb + ((size_t)bh * 2048 + kh * 1024 + kr) * 64 + ((c8 ^ (kr & 7)) * 8);
    const int kdst = kh * 4096 + qs * 2048;
    const int lv4 = lane >> 2, c4 = lane & 3;       // V: 16 rows x 4 chunks / 1KB
    const int vr = qs * 32 + lv4;
    const u16* vsrc = Vt + ((size_t)bh * 64 + vr) * 2048 + kh * 1024 + ((c4 ^ (vr & 3)) * 8);
    const int vdst = 8192 + kh * 4096 + qs * 2048;

    // LDS read offsets (per-lane constants)
    int koff[4], voff[2];
    #pragma unroll
    for (int m = 0; m < 4; ++m)
        koff[m] = kh * 4096 + q * 128 + (((2 * m + hi) ^ (q & 7)) << 4);
    #pragma unroll
    for (int kg = 0; kg < 2; ++kg)
        voff[kg] = 8192 + kh * 4096 + q * 64 + (((2 * kg + hi) ^ (q & 3)) << 4);

    f32x16 acc[2];
    #pragma unroll
    for (int i = 0; i < 2; ++i)
        #pragma unroll
        for (int r = 0; r < 16; ++r) acc[i][r] = 0.f;
    float rsum = 0.f;

    // prologue: stage tile 0 into buf 0
    gl16(ksrc,         (u16*)(smem + kdst));
    gl16(ksrc + 512,   (u16*)(smem + kdst + 1024));
    gl16(vsrc,         (u16*)(smem + vdst));
    gl16(vsrc + 32768, (u16*)(smem + vdst + 1024));
    ksrc += 2048; vsrc += 32;
    __syncthreads();

    #pragma unroll 2
    for (int it = 0; it < 32; ++it) {
        const int buf = it & 1;
        const char* bsm = smem + buf * 16384;
        if (it < 31) {
            char* nsm = smem + (buf ^ 1) * 16384;
            gl16(ksrc,         (u16*)(nsm + kdst));
            gl16(ksrc + 512,   (u16*)(nsm + kdst + 1024));
            gl16(vsrc,         (u16*)(nsm + vdst));
            gl16(vsrc + 32768, (u16*)(nsm + vdst + 1024));
            ksrc += 2048; vsrc += 32;
        }

        // QK^T: S^T (32 keys x 32 q), K rows are key positions
        f32x16 S;
        #pragma unroll
        for (int r = 0; r < 16; ++r) S[r] = 0.f;
        #pragma unroll
        for (int m = 0; m < 4; ++m) {
            U8 ak; ak.u = *(const u32x4*)(bsm + koff[m]);
            S = mfma32(ak.s, bq[m].s, S);
        }

        float p[16];
        #pragma unroll
        for (int r = 0; r < 16; ++r) p[r] = EXP2(S[r]);
        float t0 = (p[0] + p[1]) + (p[2] + p[3]);
        float t1 = (p[4] + p[5]) + (p[6] + p[7]);
        float t2 = (p[8] + p[9]) + (p[10] + p[11]);
        float t3 = (p[12] + p[13]) + (p[14] + p[15]);
        rsum += (t0 + t1) + (t2 + t3);

        U8 paA, paB;
        #pragma unroll
        for (int i = 0; i < 4; ++i) {
            paA.uw[i] = cvtpk(p[2 * i],     p[2 * i + 1]);
            paB.uw[i] = cvtpk(p[8 + 2 * i], p[9 + 2 * i]);
        }

        // PV: acc[dt2] over d = dt2*32 + q
        #pragma unroll
        for (int dt2 = 0; dt2 < 2; ++dt2) {
            U8 bv0, bv1;
            bv0.u = *(const u32x4*)(bsm + voff[0] + dt2 * 2048);
            bv1.u = *(const u32x4*)(bsm + voff[1] + dt2 * 2048);
            acc[dt2] = mfma32(paA.s, bv0.s, acc[dt2]);
            acc[dt2] = mfma32(paB.s, bv1.s, acc[dt2]);
        }
        __syncthreads();
    }

    float rsum2 = rsum + __shfl_xor(rsum, 32, 64);

    // ---- merge key-halves: kh=1 waves publish, kh=0 waves combine + write
    float* mbase = (float*)smem + qs * 2176;
    if (kh == 1) {
        #pragma unroll
        for (int dt2 = 0; dt2 < 2; ++dt2)
            #pragma unroll
            for (int r = 0; r < 16; ++r)
                mbase[(dt2 * 16 + r) * 64 + lane] = acc[dt2][r];
        mbase[2048 + lane] = rsum2;
    }
    __syncthreads();
    if (kh == 0) {
        #pragma unroll
        for (int dt2 = 0; dt2 < 2; ++dt2)
            #pragma unroll
            for (int r = 0; r < 16; ++r)
                acc[dt2][r] += mbase[(dt2 * 16 + r) * 64 + lane];
        float rtot = rsum2 + mbase[2048 + lane];
        float inv = 1.0f / rtot;
        const size_t aobase = ((size_t)b * 2048 + qbase) * 384 + h * 64;
        #pragma unroll
        for (int r = 0; r < 16; ++r) {
            const int qrow = (r & 3) + 8 * (r >> 2) + 4 * hi;
            float vinv = __shfl(inv, qrow, 64);
            #pragma unroll
            for (int dt2 = 0; dt2 < 2; ++dt2)
                AO[aobase + (size_t)qrow * 384 + dt2 * 32 + q] = f2bs(acc[dt2][r] * vinv);
        }
    }
}

// ---------------- output projection: AO[8192,384] @ Wot^T + bo -> out fp32
__global__ __launch_bounds__(256) void outproj2(const u16* __restrict__ AO,
                                                const u16* __restrict__ Wot,
                                                const float* __restrict__ bo,
                                                float* __restrict__ out) {
    __shared__ u16 As[2][64 * 32];
    __shared__ u16 Bs[2][64 * 32];
    const int tid = threadIdx.x, w = tid >> 6, lane = tid & 63;
    const int lr = lane & 15, lg = lane >> 4;
    const int wr = w >> 1, wc = w & 1;
    const int mt = blockIdx.x, nt = blockIdx.y;          // grid (128, 6)
    const int m0 = mt * 64, n0 = nt * 64;

    const int c0 = w * 64 + lane;
    const int ar0 = c0 >> 2, cc0 = c0 & 3;
    const u16* gA = AO  + (size_t)(m0 + ar0) * 384 + cc0 * 8;
    const u16* gB = Wot + (size_t)(n0 + ar0) * 384 + cc0 * 8;

    f32x4 acc[2][2];
    #pragma unroll
    for (int i = 0; i < 2; ++i)
        #pragma unroll
        for (int j = 0; j < 2; ++j) acc[i][j] = f32x4{0.f, 0.f, 0.f, 0.f};

    gl16(gA, &As[0][w * 512]);
    gl16(gB, &Bs[0][w * 512]);
    __syncthreads();

    for (int kt = 0; kt < 12; ++kt) {
        const int buf = kt & 1;
        if (kt < 11) {
            const int ko = (kt + 1) * 32;
            gl16(gA + ko, &As[buf ^ 1][w * 512]);
            gl16(gB + ko, &Bs[buf ^ 1][w * 512]);
        }
        U8 af[2], bf[2];
        #pragma unroll
        for (int f = 0; f < 2; ++f) {
            af[f].u = *(const u32x4*)&As[buf][(wr * 32 + f * 16 + lr) * 32 + lg * 8];
            bf[f].u = *(const u32x4*)&Bs[buf][(wc * 32 + f * 16 + lr) * 32 + lg * 8];
        }
        #pragma unroll
        for (int mf = 0; mf < 2; ++mf)
            #pragma unroll
            for (int nf = 0; nf < 2; ++nf)
                acc[mf][nf] = mfma16(af[mf].s, bf[nf].s, acc[mf][nf]);
        __syncthreads();
    }

    #pragma unroll
    for (int mf = 0; mf < 2; ++mf)
        #pragma unroll
        for (int nf = 0; nf < 2; ++nf) {
            int col = n0 + wc * 32 + nf * 16 + lr;
            float bias = bo[col];
            #pragma unroll
            for (int r = 0; r < 4; ++r) {
                int m = m0 + wr * 32 + mf * 16 + lg * 4 + r;
                out[(size_t)m * 384 + col] = acc[mf][nf][r] + bias;
            }
        }
}

extern "C" void kernel_launch(void* const* d_in, const int* in_sizes, int n_in,
                              void* d_out, int out_size, void* d_ws, size_t ws_size,
                              hipStream_t stream) {
    const float* x  = (const float*)d_in[0];
    const float* Wq = (const float*)d_in[1];
    const float* Wk = (const float*)d_in[2];
    const float* Wv = (const float*)d_in[3];
    const float* Wo = (const float*)d_in[4];
    const float* bo = (const float*)d_in[5];
    float* out = (float*)d_out;
    char* ws = (char*)d_ws;

    u16* Wt  = (u16*)(ws);                    // [1152][384] bf16 (Wq|Wk|Wv heads-major, then Wo^T)
    u16* Wot = (u16*)(ws + 884736);
    u16* xb  = (u16*)(ws + 1179648);          // [8192][384] bf16
    u16* Qb  = (u16*)(ws + 7471104);          // [24][2048][64] bf16
    u16* Kb  = (u16*)(ws + 13762560);
    u16* Vb  = (u16*)(ws + 20054016);
    u16* Vt  = (u16*)(ws + 26345472);         // [24][64][2048] bf16 (key positions permuted)
    u16* AO  = (u16*)(ws + 1179648);          // reuses xb slot (xb dead after proj2)

    pack_w2<<<144, 256, 0, stream>>>(Wq, Wk, Wv, Wo, Wt);
    convert_x<<<1536, 256, 0, stream>>>(x, xb);
    proj2<<<dim3(64, 9), 256, 0, stream>>>(xb, Wt, Qb, Kb, Vb);
    transpose_v<<<dim3(32, 24), 256, 0, stream>>>(Vb, Vt);
    attn4<<<dim3(24, 32), 256, 0, stream>>>(Qb, Kb, Vt, AO);
    outproj2<<<dim3(128, 6), 256, 0, stream>>>(AO, Wot, bo, out);
}